// Round 17
// baseline (199.146 us; speedup 1.0000x reference)
//
#include <hip/hip_runtime.h>
#include <stdint.h>

typedef float  f32x4   __attribute__((ext_vector_type(4)));
typedef float  float4v __attribute__((ext_vector_type(4)));
typedef short  short4v __attribute__((ext_vector_type(4)));
typedef short  short8v __attribute__((ext_vector_type(8)));
typedef __bf16 bf16x8  __attribute__((ext_vector_type(8)));

static __device__ __forceinline__ short f2bf(float f) {
  unsigned u = __builtin_bit_cast(unsigned, f);
  u += 0x7FFFu + ((u >> 16) & 1u);
  return (short)(u >> 16);
}

static __device__ __forceinline__ f32x4 mfma16(short8v a, short8v b, f32x4 c) {
  return __builtin_amdgcn_mfma_f32_16x16x32_bf16(
      __builtin_bit_cast(bf16x8, a), __builtin_bit_cast(bf16x8, b), c, 0, 0, 0);
}

static __device__ __forceinline__ short8v cat44(short4v a, short4v b) {
  short8v r;
  r[0] = a[0]; r[1] = a[1]; r[2] = a[2]; r[3] = a[3];
  r[4] = b[0]; r[5] = b[1]; r[6] = b[2]; r[7] = b[3];
  return r;
}

// Prelude A: convert qkv_w (384x128) and proj_w (128x128) f32 -> bf16.
__global__ void cvt_weights_kernel(const float* __restrict__ qkv_w,
                                   const float* __restrict__ proj_w,
                                   short* __restrict__ wq, short* __restrict__ wp) {
  int i = blockIdx.x * 256 + threadIdx.x;   // grid = 192 blocks -> 49152
  wq[i] = f2bf(qkv_w[i]);
  if (i < 16384) wp[i] = f2bf(proj_w[i]);
}

// Prelude B: combined bias+mask table laid out as the MFMA S-fragment:
// cmb[w(64)][h(4)][qt(4)][i(4)][lane(64)][r(4)] f32  (4 MB)
__global__ void build_cmb_kernel(const float* __restrict__ mask,
                                 const float* __restrict__ bias_table,
                                 float* __restrict__ cmb) {
  int id   = blockIdx.x * 256 + threadIdx.x;   // grid = 1024 blocks
  int lane = id & 63;
  int i    = (id >> 6) & 3;
  int qt   = (id >> 8) & 3;
  int h    = (id >> 10) & 3;
  int w    = id >> 12;
  int q     = qt * 16 + (lane & 15);
  int kbase = i * 16 + ((lane >> 4) << 2);
  f32x4 v;
#pragma unroll
  for (int r = 0; r < 4; ++r) {
    int key = kbase + r;
    float val;
    if (key >= 49) {
      val = -1e30f;
    } else if (q >= 49) {
      val = 0.f;
    } else {
      int qi = q / 7, qj = q - qi * 7;
      int ki = key / 7, kj = key - ki * 7;
      int ridx = (qi - ki + 6) * 13 + (qj - kj + 6);
      val = bias_table[ridx * 4 + h] + mask[w * 2401 + q * 49 + key];
    }
    v[r] = val;
  }
  ((f32x4*)cmb)[id] = v;
}

// One block = one window; 256 threads = 4 waves; wave = head h, ALL 64 tokens.
// R17 = R16 (PV streams to LDS, ~84 VGPR demand) + R12's aom<->xb alias:
// LDS 34816 B -> 4 blocks/CU at (256,4) (budget 128 >> 84 demand, unlike
// R9 whose o[2][4]-held-across-barrier structure needed ~150 and spilled).
// 3 barriers: B1 stage, B2 xb-reads-done (aom may overwrite), B3 aom-ready.
__global__ __launch_bounds__(256, 4)
void win_attn_kernel(const float* __restrict__ x,
                     const float* __restrict__ qkv_b,
                     const float* __restrict__ proj_b,
                     const short* __restrict__ wq,
                     const short* __restrict__ wp,
                     const float* __restrict__ cmb,
                     float* __restrict__ out) {
  __shared__ __align__(16) short smem[17408];   // 34816 B
  short* xb  = smem;            // [64][136]          [0, 8704)
  short* vtm = smem + 8704;     // [4][32][68] v^T    [8704, 17408)
  short* aom = smem;            // ALIAS xb after B2

  const int b    = blockIdx.x;
  const int tid  = threadIdx.x;
  const int lane = tid & 63;
  const int h    = tid >> 6;    // wave = head
  const int l15  = lane & 15;
  const int lhi  = lane >> 4;
  const int cb   = lhi * 8;

  // ---- Phase 0: stage x -> bf16 LDS, zero pad rows 49..63
  {
    short4v z = {0, 0, 0, 0};
    for (int idx = tid; idx < 510; idx += 256)
      *(short4v*)&xb[49 * 136 + idx * 4] = z;
    const float* xw = x + (long)b * (49 * 128);
    for (int idx = tid; idx < 1568; idx += 256) {
      int m  = idx >> 5;
      int c0 = (idx & 31) << 2;
      float4v v = *(const float4v*)&xw[m * 128 + c0];
      short4v s;
      s[0] = f2bf(v[0]); s[1] = f2bf(v[1]); s[2] = f2bf(v[2]); s[3] = f2bf(v[3]);
      *(short4v*)&xb[m * 136 + c0] = s;
    }
  }
  __syncthreads();   // B1

  // ---- Phase 1a: Q+K projection (swapped: acc = [wcol][token]), 64 tokens.
  short8v qfr[4], kfr[4];
  {
    f32x4 qa[2][4], ka[2][4];   // [nt][jt]
#pragma unroll
    for (int nt = 0; nt < 2; ++nt) {
      const f32x4 bq4 = *(const f32x4*)&qkv_b[h * 32 + nt * 16 + lhi * 4];
      const f32x4 bk4 = *(const f32x4*)&qkv_b[128 + h * 32 + nt * 16 + lhi * 4];
#pragma unroll
      for (int jt = 0; jt < 4; ++jt) { qa[nt][jt] = bq4; ka[nt][jt] = bk4; }
    }
#pragma unroll
    for (int ks = 0; ks < 4; ++ks) {
      short8v a[4];
#pragma unroll
      for (int jt = 0; jt < 4; ++jt)
        a[jt] = *(const short8v*)&xb[(jt * 16 + l15) * 136 + ks * 32 + cb];
#pragma unroll
      for (int nt = 0; nt < 2; ++nt) {
        const short8v bq =
            *(const short8v*)&wq[(h * 32 + nt * 16 + l15) * 128 + ks * 32 + cb];
        const short8v bk =
            *(const short8v*)&wq[(128 + h * 32 + nt * 16 + l15) * 128 + ks * 32 + cb];
#pragma unroll
        for (int jt = 0; jt < 4; ++jt) {
          qa[nt][jt] = mfma16(bq, a[jt], qa[nt][jt]);
          ka[nt][jt] = mfma16(bk, a[jt], ka[nt][jt]);
        }
      }
    }
    const float scale = 0.1767766952966369f;  // 32^-0.5
#pragma unroll
    for (int jt = 0; jt < 4; ++jt) {
      short8v qv, kv;
#pragma unroll
      for (int nt = 0; nt < 2; ++nt)
#pragma unroll
        for (int r = 0; r < 4; ++r) {
          qv[nt * 4 + r] = f2bf(qa[nt][jt][r] * scale);
          kv[nt * 4 + r] = f2bf(ka[nt][jt][r]);
        }
      qfr[jt] = qv;
      kfr[jt] = kv;
    }
  }

  // ---- Phase 1b: V projection (normal), store transposed to OWN vtm slice.
  {
    f32x4 va[2][4];   // [nt][mt]
#pragma unroll
    for (int nt = 0; nt < 2; ++nt) {
      const float vb = qkv_b[256 + h * 32 + nt * 16 + l15];
#pragma unroll
      for (int mt = 0; mt < 4; ++mt) va[nt][mt] = f32x4{vb, vb, vb, vb};
    }
#pragma unroll
    for (int ks = 0; ks < 4; ++ks) {
      short8v a[4];
#pragma unroll
      for (int mt = 0; mt < 4; ++mt)
        a[mt] = *(const short8v*)&xb[(mt * 16 + l15) * 136 + ks * 32 + cb];
#pragma unroll
      for (int nt = 0; nt < 2; ++nt) {
        const short8v bv =
            *(const short8v*)&wq[(256 + h * 32 + nt * 16 + l15) * 128 + ks * 32 + cb];
#pragma unroll
        for (int mt = 0; mt < 4; ++mt)
          va[nt][mt] = mfma16(a[mt], bv, va[nt][mt]);
      }
    }
#pragma unroll
    for (int nt = 0; nt < 2; ++nt)
#pragma unroll
      for (int mt = 0; mt < 4; ++mt) {
        short4v p;
#pragma unroll
        for (int r = 0; r < 4; ++r) p[r] = f2bf(va[nt][mt][r]);
        *(short4v*)&vtm[h * 2176 + (nt * 16 + l15) * 68 + mt * 16 + lhi * 4] = p;
      }
  }
  __syncthreads();   // B2: all xb reads done; aom (== xb) may be overwritten

  // ---- Phase 2: S = mfma(K,Q) + cmb; in-lane softmax; PV -> aom directly.
  {
    const f32x4* cmb4 = (const f32x4*)cmb;
    const long cbase = (long)(b & 63) * 4096 + h * 1024 + lane;

#pragma unroll
    for (int jt = 0; jt < 4; ++jt) {
      f32x4 s[4];
#pragma unroll
      for (int i = 0; i < 4; ++i)
        s[i] = mfma16(kfr[i], qfr[jt], cmb4[cbase + jt * 256 + i * 64]);

      float mx = s[0][0];
#pragma unroll
      for (int i = 0; i < 4; ++i)
#pragma unroll
        for (int r = 0; r < 4; ++r) mx = fmaxf(mx, s[i][r]);
      mx = fmaxf(mx, __shfl_xor(mx, 16));
      mx = fmaxf(mx, __shfl_xor(mx, 32));
      float sum = 0.f;
#pragma unroll
      for (int i = 0; i < 4; ++i)
#pragma unroll
        for (int r = 0; r < 4; ++r) {
          float e = __expf(s[i][r] - mx);
          s[i][r] = e;
          sum += e;
        }
      sum += __shfl_xor(sum, 16);
      sum += __shfl_xor(sum, 32);
      const float inv = 1.f / sum;

      short8v pb[2];
#pragma unroll
      for (int ks = 0; ks < 2; ++ks) {
        short8v pv;
#pragma unroll
        for (int e = 0; e < 4; ++e) pv[e]     = f2bf(s[2 * ks][e] * inv);
#pragma unroll
        for (int e = 0; e < 4; ++e) pv[4 + e] = f2bf(s[2 * ks + 1][e] * inv);
        pb[ks] = pv;
      }

#pragma unroll
      for (int dt = 0; dt < 2; ++dt) {
        f32x4 o = {0.f, 0.f, 0.f, 0.f};
#pragma unroll
        for (int ks = 0; ks < 2; ++ks) {
          const int va = h * 2176 + (dt * 16 + l15) * 68 + ks * 32 + lhi * 4;
          short8v vfr = cat44(*(const short4v*)&vtm[va], *(const short4v*)&vtm[va + 16]);
          o = mfma16(vfr, pb[ks], o);
        }
        short4v p;
#pragma unroll
        for (int r = 0; r < 4; ++r) p[r] = f2bf(o[r]);
        *(short4v*)&aom[(jt * 16 + l15) * 136 + h * 32 + dt * 16 + lhi * 4] = p;
      }
    }
  }
  __syncthreads();   // B3: aom complete (all heads' columns visible)

  // ---- Phase 3: output projection Y = AO @ proj_w^T + proj_b (ks-outer)
  {
    f32x4 po[2][4];   // [nt][mt]
#pragma unroll
    for (int nt = 0; nt < 2; ++nt) {
      const float pbv = proj_b[h * 32 + nt * 16 + l15];
#pragma unroll
      for (int mt = 0; mt < 4; ++mt) po[nt][mt] = f32x4{pbv, pbv, pbv, pbv};
    }
#pragma unroll
    for (int ks = 0; ks < 4; ++ks) {
      short8v p[4];
#pragma unroll
      for (int mt = 0; mt < 4; ++mt)
        p[mt] = *(const short8v*)&aom[(mt * 16 + l15) * 136 + ks * 32 + cb];
#pragma unroll
      for (int nt = 0; nt < 2; ++nt) {
        const short8v wfr =
            *(const short8v*)&wp[(h * 32 + nt * 16 + l15) * 128 + ks * 32 + cb];
#pragma unroll
        for (int mt = 0; mt < 4; ++mt)
          po[nt][mt] = mfma16(p[mt], wfr, po[nt][mt]);
      }
    }
    float* outw = out + (long)b * (49 * 128);
#pragma unroll
    for (int nt = 0; nt < 2; ++nt) {
      const int ncol = h * 32 + nt * 16 + l15;
#pragma unroll
      for (int mt = 0; mt < 4; ++mt)
#pragma unroll
        for (int r = 0; r < 4; ++r) {
          const int m0 = mt * 16 + lhi * 4 + r;
          if (m0 < 49) outw[m0 * 128 + ncol] = po[nt][mt][r];
        }
    }
  }
}

extern "C" void kernel_launch(void* const* d_in, const int* in_sizes, int n_in,
                              void* d_out, int out_size, void* d_ws, size_t ws_size,
                              hipStream_t stream) {
  const float* x          = (const float*)d_in[0];
  const float* mask       = (const float*)d_in[1];
  const float* qkv_w      = (const float*)d_in[2];
  const float* qkv_b      = (const float*)d_in[3];
  const float* proj_w     = (const float*)d_in[4];
  const float* proj_b     = (const float*)d_in[5];
  const float* bias_table = (const float*)d_in[6];

  short* wq  = (short*)d_ws;                         // 384*128 bf16 (98304 B)
  short* wp  = wq + 49152;                           // 128*128 bf16 (32768 B)
  float* cmb = (float*)((char*)d_ws + 131072);       // 4 MB combined bias+mask

  cvt_weights_kernel<<<dim3(192), dim3(256), 0, stream>>>(qkv_w, proj_w, wq, wp);
  build_cmb_kernel<<<dim3(1024), dim3(256), 0, stream>>>(mask, bias_table, cmb);
  win_attn_kernel<<<dim3(4096), dim3(256), 0, stream>>>(
      x, qkv_b, proj_b, wq, wp, cmb, (float*)d_out);
}

// Round 18
// 110.622 us; speedup vs baseline: 1.8002x; 1.8002x over previous
//
#include <hip/hip_runtime.h>
#include <stdint.h>

typedef float  f32x4   __attribute__((ext_vector_type(4)));
typedef float  float4v __attribute__((ext_vector_type(4)));
typedef short  short4v __attribute__((ext_vector_type(4)));
typedef short  short8v __attribute__((ext_vector_type(8)));
typedef __bf16 bf16x8  __attribute__((ext_vector_type(8)));

static __device__ __forceinline__ short f2bf(float f) {
  unsigned u = __builtin_bit_cast(unsigned, f);
  u += 0x7FFFu + ((u >> 16) & 1u);
  return (short)(u >> 16);
}

static __device__ __forceinline__ f32x4 mfma16(short8v a, short8v b, f32x4 c) {
  return __builtin_amdgcn_mfma_f32_16x16x32_bf16(
      __builtin_bit_cast(bf16x8, a), __builtin_bit_cast(bf16x8, b), c, 0, 0, 0);
}

static __device__ __forceinline__ short8v cat44(short4v a, short4v b) {
  short8v r;
  r[0] = a[0]; r[1] = a[1]; r[2] = a[2]; r[3] = a[3];
  r[4] = b[0]; r[5] = b[1]; r[6] = b[2]; r[7] = b[3];
  return r;
}

// Prelude A: convert qkv_w (384x128) and proj_w (128x128) f32 -> bf16.
__global__ void cvt_weights_kernel(const float* __restrict__ qkv_w,
                                   const float* __restrict__ proj_w,
                                   short* __restrict__ wq, short* __restrict__ wp) {
  int i = blockIdx.x * 256 + threadIdx.x;   // grid = 192 blocks -> 49152
  wq[i] = f2bf(qkv_w[i]);
  if (i < 16384) wp[i] = f2bf(proj_w[i]);
}

// Prelude B: combined bias+mask table laid out as the MFMA S-fragment:
// cmb[w(64)][h(4)][qt(4)][i(4)][lane(64)][r(4)] f32  (4 MB)
__global__ void build_cmb_kernel(const float* __restrict__ mask,
                                 const float* __restrict__ bias_table,
                                 float* __restrict__ cmb) {
  int id   = blockIdx.x * 256 + threadIdx.x;   // grid = 1024 blocks
  int lane = id & 63;
  int i    = (id >> 6) & 3;
  int qt   = (id >> 8) & 3;
  int h    = (id >> 10) & 3;
  int w    = id >> 12;
  int q     = qt * 16 + (lane & 15);
  int kbase = i * 16 + ((lane >> 4) << 2);
  f32x4 v;
#pragma unroll
  for (int r = 0; r < 4; ++r) {
    int key = kbase + r;
    float val;
    if (key >= 49) {
      val = -1e30f;
    } else if (q >= 49) {
      val = 0.f;
    } else {
      int qi = q / 7, qj = q - qi * 7;
      int ki = key / 7, kj = key - ki * 7;
      int ridx = (qi - ki + 6) * 13 + (qj - kj + 6);
      val = bias_table[ridx * 4 + h] + mask[w * 2401 + q * 49 + key];
    }
    v[r] = val;
  }
  ((f32x4*)cmb)[id] = v;
}

// One block = one window; 256 threads = 4 waves; wave = head h, ALL 64 tokens.
// R18 = R17's layout (aom aliases xb, LDS 34816 B) with R16's PROVEN
// __launch_bounds__(256,3). Rule learned (R5/R9/R17): min-waves>=4 in
// launch_bounds makes the allocator clamp to 64 arch-VGPRs and spill.
// (256,3) reproduces R16's 84-reg allocation; since 84 <= 128, HARDWARE
// residency is 4 waves/SIMD (m69), and LDS 34816*4 <= 160 KiB -> 4 blocks/CU.
// 3 barriers: B1 stage, B2 xb-reads-done (aom may overwrite), B3 aom-ready.
__global__ __launch_bounds__(256, 3)
void win_attn_kernel(const float* __restrict__ x,
                     const float* __restrict__ qkv_b,
                     const float* __restrict__ proj_b,
                     const short* __restrict__ wq,
                     const short* __restrict__ wp,
                     const float* __restrict__ cmb,
                     float* __restrict__ out) {
  __shared__ __align__(16) short smem[17408];   // 34816 B
  short* xb  = smem;            // [64][136]          [0, 8704)
  short* vtm = smem + 8704;     // [4][32][68] v^T    [8704, 17408)
  short* aom = smem;            // ALIAS xb after B2

  const int b    = blockIdx.x;
  const int tid  = threadIdx.x;
  const int lane = tid & 63;
  const int h    = tid >> 6;    // wave = head
  const int l15  = lane & 15;
  const int lhi  = lane >> 4;
  const int cb   = lhi * 8;

  // ---- Phase 0: stage x -> bf16 LDS, zero pad rows 49..63
  {
    short4v z = {0, 0, 0, 0};
    for (int idx = tid; idx < 510; idx += 256)
      *(short4v*)&xb[49 * 136 + idx * 4] = z;
    const float* xw = x + (long)b * (49 * 128);
    for (int idx = tid; idx < 1568; idx += 256) {
      int m  = idx >> 5;
      int c0 = (idx & 31) << 2;
      float4v v = *(const float4v*)&xw[m * 128 + c0];
      short4v s;
      s[0] = f2bf(v[0]); s[1] = f2bf(v[1]); s[2] = f2bf(v[2]); s[3] = f2bf(v[3]);
      *(short4v*)&xb[m * 136 + c0] = s;
    }
  }
  __syncthreads();   // B1

  // ---- Phase 1a: Q+K projection (swapped: acc = [wcol][token]), 64 tokens.
  short8v qfr[4], kfr[4];
  {
    f32x4 qa[2][4], ka[2][4];   // [nt][jt]
#pragma unroll
    for (int nt = 0; nt < 2; ++nt) {
      const f32x4 bq4 = *(const f32x4*)&qkv_b[h * 32 + nt * 16 + lhi * 4];
      const f32x4 bk4 = *(const f32x4*)&qkv_b[128 + h * 32 + nt * 16 + lhi * 4];
#pragma unroll
      for (int jt = 0; jt < 4; ++jt) { qa[nt][jt] = bq4; ka[nt][jt] = bk4; }
    }
#pragma unroll
    for (int ks = 0; ks < 4; ++ks) {
      short8v a[4];
#pragma unroll
      for (int jt = 0; jt < 4; ++jt)
        a[jt] = *(const short8v*)&xb[(jt * 16 + l15) * 136 + ks * 32 + cb];
#pragma unroll
      for (int nt = 0; nt < 2; ++nt) {
        const short8v bq =
            *(const short8v*)&wq[(h * 32 + nt * 16 + l15) * 128 + ks * 32 + cb];
        const short8v bk =
            *(const short8v*)&wq[(128 + h * 32 + nt * 16 + l15) * 128 + ks * 32 + cb];
#pragma unroll
        for (int jt = 0; jt < 4; ++jt) {
          qa[nt][jt] = mfma16(bq, a[jt], qa[nt][jt]);
          ka[nt][jt] = mfma16(bk, a[jt], ka[nt][jt]);
        }
      }
    }
    const float scale = 0.1767766952966369f;  // 32^-0.5
#pragma unroll
    for (int jt = 0; jt < 4; ++jt) {
      short8v qv, kv;
#pragma unroll
      for (int nt = 0; nt < 2; ++nt)
#pragma unroll
        for (int r = 0; r < 4; ++r) {
          qv[nt * 4 + r] = f2bf(qa[nt][jt][r] * scale);
          kv[nt * 4 + r] = f2bf(ka[nt][jt][r]);
        }
      qfr[jt] = qv;
      kfr[jt] = kv;
    }
  }

  // ---- Phase 1b: V projection (normal), store transposed to OWN vtm slice.
  {
    f32x4 va[2][4];   // [nt][mt]
#pragma unroll
    for (int nt = 0; nt < 2; ++nt) {
      const float vb = qkv_b[256 + h * 32 + nt * 16 + l15];
#pragma unroll
      for (int mt = 0; mt < 4; ++mt) va[nt][mt] = f32x4{vb, vb, vb, vb};
    }
#pragma unroll
    for (int ks = 0; ks < 4; ++ks) {
      short8v a[4];
#pragma unroll
      for (int mt = 0; mt < 4; ++mt)
        a[mt] = *(const short8v*)&xb[(mt * 16 + l15) * 136 + ks * 32 + cb];
#pragma unroll
      for (int nt = 0; nt < 2; ++nt) {
        const short8v bv =
            *(const short8v*)&wq[(256 + h * 32 + nt * 16 + l15) * 128 + ks * 32 + cb];
#pragma unroll
        for (int mt = 0; mt < 4; ++mt)
          va[nt][mt] = mfma16(a[mt], bv, va[nt][mt]);
      }
    }
#pragma unroll
    for (int nt = 0; nt < 2; ++nt)
#pragma unroll
      for (int mt = 0; mt < 4; ++mt) {
        short4v p;
#pragma unroll
        for (int r = 0; r < 4; ++r) p[r] = f2bf(va[nt][mt][r]);
        *(short4v*)&vtm[h * 2176 + (nt * 16 + l15) * 68 + mt * 16 + lhi * 4] = p;
      }
  }
  __syncthreads();   // B2: all xb reads done; aom (== xb) may be overwritten

  // ---- Phase 2: S = mfma(K,Q) + cmb; in-lane softmax; PV -> aom directly.
  {
    const f32x4* cmb4 = (const f32x4*)cmb;
    const long cbase = (long)(b & 63) * 4096 + h * 1024 + lane;

#pragma unroll
    for (int jt = 0; jt < 4; ++jt) {
      f32x4 s[4];
#pragma unroll
      for (int i = 0; i < 4; ++i)
        s[i] = mfma16(kfr[i], qfr[jt], cmb4[cbase + jt * 256 + i * 64]);

      float mx = s[0][0];
#pragma unroll
      for (int i = 0; i < 4; ++i)
#pragma unroll
        for (int r = 0; r < 4; ++r) mx = fmaxf(mx, s[i][r]);
      mx = fmaxf(mx, __shfl_xor(mx, 16));
      mx = fmaxf(mx, __shfl_xor(mx, 32));
      float sum = 0.f;
#pragma unroll
      for (int i = 0; i < 4; ++i)
#pragma unroll
        for (int r = 0; r < 4; ++r) {
          float e = __expf(s[i][r] - mx);
          s[i][r] = e;
          sum += e;
        }
      sum += __shfl_xor(sum, 16);
      sum += __shfl_xor(sum, 32);
      const float inv = 1.f / sum;

      short8v pb[2];
#pragma unroll
      for (int ks = 0; ks < 2; ++ks) {
        short8v pv;
#pragma unroll
        for (int e = 0; e < 4; ++e) pv[e]     = f2bf(s[2 * ks][e] * inv);
#pragma unroll
        for (int e = 0; e < 4; ++e) pv[4 + e] = f2bf(s[2 * ks + 1][e] * inv);
        pb[ks] = pv;
      }

#pragma unroll
      for (int dt = 0; dt < 2; ++dt) {
        f32x4 o = {0.f, 0.f, 0.f, 0.f};
#pragma unroll
        for (int ks = 0; ks < 2; ++ks) {
          const int va = h * 2176 + (dt * 16 + l15) * 68 + ks * 32 + lhi * 4;
          short8v vfr = cat44(*(const short4v*)&vtm[va], *(const short4v*)&vtm[va + 16]);
          o = mfma16(vfr, pb[ks], o);
        }
        short4v p;
#pragma unroll
        for (int r = 0; r < 4; ++r) p[r] = f2bf(o[r]);
        *(short4v*)&aom[(jt * 16 + l15) * 136 + h * 32 + dt * 16 + lhi * 4] = p;
      }
    }
  }
  __syncthreads();   // B3: aom complete (all heads' columns visible)

  // ---- Phase 3: output projection Y = AO @ proj_w^T + proj_b (ks-outer)
  {
    f32x4 po[2][4];   // [nt][mt]
#pragma unroll
    for (int nt = 0; nt < 2; ++nt) {
      const float pbv = proj_b[h * 32 + nt * 16 + l15];
#pragma unroll
      for (int mt = 0; mt < 4; ++mt) po[nt][mt] = f32x4{pbv, pbv, pbv, pbv};
    }
#pragma unroll
    for (int ks = 0; ks < 4; ++ks) {
      short8v p[4];
#pragma unroll
      for (int mt = 0; mt < 4; ++mt)
        p[mt] = *(const short8v*)&aom[(mt * 16 + l15) * 136 + ks * 32 + cb];
#pragma unroll
      for (int nt = 0; nt < 2; ++nt) {
        const short8v wfr =
            *(const short8v*)&wp[(h * 32 + nt * 16 + l15) * 128 + ks * 32 + cb];
#pragma unroll
        for (int mt = 0; mt < 4; ++mt)
          po[nt][mt] = mfma16(p[mt], wfr, po[nt][mt]);
      }
    }
    float* outw = out + (long)b * (49 * 128);
#pragma unroll
    for (int nt = 0; nt < 2; ++nt) {
      const int ncol = h * 32 + nt * 16 + l15;
#pragma unroll
      for (int mt = 0; mt < 4; ++mt)
#pragma unroll
        for (int r = 0; r < 4; ++r) {
          const int m0 = mt * 16 + lhi * 4 + r;
          if (m0 < 49) outw[m0 * 128 + ncol] = po[nt][mt][r];
        }
    }
  }
}

extern "C" void kernel_launch(void* const* d_in, const int* in_sizes, int n_in,
                              void* d_out, int out_size, void* d_ws, size_t ws_size,
                              hipStream_t stream) {
  const float* x          = (const float*)d_in[0];
  const float* mask       = (const float*)d_in[1];
  const float* qkv_w      = (const float*)d_in[2];
  const float* qkv_b      = (const float*)d_in[3];
  const float* proj_w     = (const float*)d_in[4];
  const float* proj_b     = (const float*)d_in[5];
  const float* bias_table = (const float*)d_in[6];

  short* wq  = (short*)d_ws;                         // 384*128 bf16 (98304 B)
  short* wp  = wq + 49152;                           // 128*128 bf16 (32768 B)
  float* cmb = (float*)((char*)d_ws + 131072);       // 4 MB combined bias+mask

  cvt_weights_kernel<<<dim3(192), dim3(256), 0, stream>>>(qkv_w, proj_w, wq, wp);
  build_cmb_kernel<<<dim3(1024), dim3(256), 0, stream>>>(mask, bias_table, cmb);
  win_attn_kernel<<<dim3(4096), dim3(256), 0, stream>>>(
      x, qkv_b, proj_b, wq, wp, cmb, (float*)d_out);
}

// Round 19
// 105.131 us; speedup vs baseline: 1.8943x; 1.0522x over previous
//
#include <hip/hip_runtime.h>
#include <stdint.h>

typedef float  f32x4   __attribute__((ext_vector_type(4)));
typedef float  float4v __attribute__((ext_vector_type(4)));
typedef short  short4v __attribute__((ext_vector_type(4)));
typedef short  short8v __attribute__((ext_vector_type(8)));
typedef __bf16 bf16x8  __attribute__((ext_vector_type(8)));

static __device__ __forceinline__ short f2bf(float f) {
  unsigned u = __builtin_bit_cast(unsigned, f);
  u += 0x7FFFu + ((u >> 16) & 1u);
  return (short)(u >> 16);
}

static __device__ __forceinline__ f32x4 mfma16(short8v a, short8v b, f32x4 c) {
  return __builtin_amdgcn_mfma_f32_16x16x32_bf16(
      __builtin_bit_cast(bf16x8, a), __builtin_bit_cast(bf16x8, b), c, 0, 0, 0);
}

static __device__ __forceinline__ short8v cat44(short4v a, short4v b) {
  short8v r;
  r[0] = a[0]; r[1] = a[1]; r[2] = a[2]; r[3] = a[3];
  r[4] = b[0]; r[5] = b[1]; r[6] = b[2]; r[7] = b[3];
  return r;
}

// Prelude A: convert qkv_w (384x128) and proj_w (128x128) f32 -> bf16.
__global__ void cvt_weights_kernel(const float* __restrict__ qkv_w,
                                   const float* __restrict__ proj_w,
                                   short* __restrict__ wq, short* __restrict__ wp) {
  int i = blockIdx.x * 256 + threadIdx.x;   // grid = 192 blocks -> 49152
  wq[i] = f2bf(qkv_w[i]);
  if (i < 16384) wp[i] = f2bf(proj_w[i]);
}

// Prelude B: combined bias+mask table laid out as the MFMA S-fragment:
// cmb[w(64)][h(4)][qt(4)][i(4)][lane(64)][r(4)] f32  (4 MB)
__global__ void build_cmb_kernel(const float* __restrict__ mask,
                                 const float* __restrict__ bias_table,
                                 float* __restrict__ cmb) {
  int id   = blockIdx.x * 256 + threadIdx.x;   // grid = 1024 blocks
  int lane = id & 63;
  int i    = (id >> 6) & 3;
  int qt   = (id >> 8) & 3;
  int h    = (id >> 10) & 3;
  int w    = id >> 12;
  int q     = qt * 16 + (lane & 15);
  int kbase = i * 16 + ((lane >> 4) << 2);
  f32x4 v;
#pragma unroll
  for (int r = 0; r < 4; ++r) {
    int key = kbase + r;
    float val;
    if (key >= 49) {
      val = -1e30f;
    } else if (q >= 49) {
      val = 0.f;
    } else {
      int qi = q / 7, qj = q - qi * 7;
      int ki = key / 7, kj = key - ki * 7;
      int ridx = (qi - ki + 6) * 13 + (qj - kj + 6);
      val = bias_table[ridx * 4 + h] + mask[w * 2401 + q * 49 + key];
    }
    v[r] = val;
  }
  ((f32x4*)cmb)[id] = v;
}

// One block = one window; 256 threads = 4 waves; wave = head h, ALL 64 tokens.
// R19 = R18 + nt-split of phase 1a: two sequential passes (nt=0, nt=1), each
// holding only qa[4]+ka[4] = 32 acc regs (was 64). Unified reg demand drops
// ~148 -> ~116 <= 128 -> HARDWARE gives 4 waves/SIMD (the R18 limiter was
// the unified VGPR+AGPR total, not LDS). sched_barrier(0) between passes
// stops the scheduler from re-merging them. LDS 34816 B (4 blocks fit).
// 3 barriers: B1 stage, B2 xb-reads-done (aom may overwrite), B3 aom-ready.
__global__ __launch_bounds__(256, 3)
void win_attn_kernel(const float* __restrict__ x,
                     const float* __restrict__ qkv_b,
                     const float* __restrict__ proj_b,
                     const short* __restrict__ wq,
                     const short* __restrict__ wp,
                     const float* __restrict__ cmb,
                     float* __restrict__ out) {
  __shared__ __align__(16) short smem[17408];   // 34816 B
  short* xb  = smem;            // [64][136]          [0, 8704)
  short* vtm = smem + 8704;     // [4][32][68] v^T    [8704, 17408)
  short* aom = smem;            // ALIAS xb after B2

  const int b    = blockIdx.x;
  const int tid  = threadIdx.x;
  const int lane = tid & 63;
  const int h    = tid >> 6;    // wave = head
  const int l15  = lane & 15;
  const int lhi  = lane >> 4;
  const int cb   = lhi * 8;

  // ---- Phase 0: stage x -> bf16 LDS, zero pad rows 49..63
  {
    short4v z = {0, 0, 0, 0};
    for (int idx = tid; idx < 510; idx += 256)
      *(short4v*)&xb[49 * 136 + idx * 4] = z;
    const float* xw = x + (long)b * (49 * 128);
    for (int idx = tid; idx < 1568; idx += 256) {
      int m  = idx >> 5;
      int c0 = (idx & 31) << 2;
      float4v v = *(const float4v*)&xw[m * 128 + c0];
      short4v s;
      s[0] = f2bf(v[0]); s[1] = f2bf(v[1]); s[2] = f2bf(v[2]); s[3] = f2bf(v[3]);
      *(short4v*)&xb[m * 136 + c0] = s;
    }
  }
  __syncthreads();   // B1

  // ---- Phase 1a: Q+K projection (swapped), nt-split into two 32-acc passes.
  short8v qfr[4], kfr[4];
  const float scale = 0.1767766952966369f;  // 32^-0.5
#define QKPASS(NT)                                                             \
  {                                                                            \
    f32x4 qa[4], ka[4];                                                        \
    const f32x4 bq4 = *(const f32x4*)&qkv_b[h * 32 + (NT)*16 + lhi * 4];       \
    const f32x4 bk4 = *(const f32x4*)&qkv_b[128 + h * 32 + (NT)*16 + lhi * 4]; \
    _Pragma("unroll")                                                          \
    for (int jt = 0; jt < 4; ++jt) { qa[jt] = bq4; ka[jt] = bk4; }             \
    _Pragma("unroll")                                                          \
    for (int ks = 0; ks < 4; ++ks) {                                           \
      short8v a[4];                                                            \
      _Pragma("unroll")                                                        \
      for (int jt = 0; jt < 4; ++jt)                                           \
        a[jt] = *(const short8v*)&xb[(jt * 16 + l15) * 136 + ks * 32 + cb];    \
      const short8v bq = *(const short8v*)                                     \
          &wq[(h * 32 + (NT)*16 + l15) * 128 + ks * 32 + cb];                  \
      const short8v bk = *(const short8v*)                                     \
          &wq[(128 + h * 32 + (NT)*16 + l15) * 128 + ks * 32 + cb];            \
      _Pragma("unroll")                                                        \
      for (int jt = 0; jt < 4; ++jt) {                                         \
        qa[jt] = mfma16(bq, a[jt], qa[jt]);                                    \
        ka[jt] = mfma16(bk, a[jt], ka[jt]);                                    \
      }                                                                        \
    }                                                                          \
    _Pragma("unroll")                                                          \
    for (int jt = 0; jt < 4; ++jt)                                             \
      _Pragma("unroll")                                                        \
      for (int r = 0; r < 4; ++r) {                                            \
        qfr[jt][(NT)*4 + r] = f2bf(qa[jt][r] * scale);                         \
        kfr[jt][(NT)*4 + r] = f2bf(ka[jt][r]);                                 \
      }                                                                        \
  }
  QKPASS(0)
  __builtin_amdgcn_sched_barrier(0);   // keep pass acc sets disjoint
  QKPASS(1)
  __builtin_amdgcn_sched_barrier(0);
#undef QKPASS

  // ---- Phase 1b: V projection (normal), store transposed to OWN vtm slice.
  {
    f32x4 va[2][4];   // [nt][mt] = 32 acc regs
#pragma unroll
    for (int nt = 0; nt < 2; ++nt) {
      const float vb = qkv_b[256 + h * 32 + nt * 16 + l15];
#pragma unroll
      for (int mt = 0; mt < 4; ++mt) va[nt][mt] = f32x4{vb, vb, vb, vb};
    }
#pragma unroll
    for (int ks = 0; ks < 4; ++ks) {
      short8v a[4];
#pragma unroll
      for (int mt = 0; mt < 4; ++mt)
        a[mt] = *(const short8v*)&xb[(mt * 16 + l15) * 136 + ks * 32 + cb];
#pragma unroll
      for (int nt = 0; nt < 2; ++nt) {
        const short8v bv =
            *(const short8v*)&wq[(256 + h * 32 + nt * 16 + l15) * 128 + ks * 32 + cb];
#pragma unroll
        for (int mt = 0; mt < 4; ++mt)
          va[nt][mt] = mfma16(a[mt], bv, va[nt][mt]);
      }
    }
#pragma unroll
    for (int nt = 0; nt < 2; ++nt)
#pragma unroll
      for (int mt = 0; mt < 4; ++mt) {
        short4v p;
#pragma unroll
        for (int r = 0; r < 4; ++r) p[r] = f2bf(va[nt][mt][r]);
        *(short4v*)&vtm[h * 2176 + (nt * 16 + l15) * 68 + mt * 16 + lhi * 4] = p;
      }
  }
  __syncthreads();   // B2: all xb reads done; aom (== xb) may be overwritten

  // ---- Phase 2: S = mfma(K,Q) + cmb; in-lane softmax; PV -> aom directly.
  {
    const f32x4* cmb4 = (const f32x4*)cmb;
    const long cbase = (long)(b & 63) * 4096 + h * 1024 + lane;

#pragma unroll
    for (int jt = 0; jt < 4; ++jt) {
      f32x4 s[4];
#pragma unroll
      for (int i = 0; i < 4; ++i)
        s[i] = mfma16(kfr[i], qfr[jt], cmb4[cbase + jt * 256 + i * 64]);

      float mx = s[0][0];
#pragma unroll
      for (int i = 0; i < 4; ++i)
#pragma unroll
        for (int r = 0; r < 4; ++r) mx = fmaxf(mx, s[i][r]);
      mx = fmaxf(mx, __shfl_xor(mx, 16));
      mx = fmaxf(mx, __shfl_xor(mx, 32));
      float sum = 0.f;
#pragma unroll
      for (int i = 0; i < 4; ++i)
#pragma unroll
        for (int r = 0; r < 4; ++r) {
          float e = __expf(s[i][r] - mx);
          s[i][r] = e;
          sum += e;
        }
      sum += __shfl_xor(sum, 16);
      sum += __shfl_xor(sum, 32);
      const float inv = 1.f / sum;

      short8v pb[2];
#pragma unroll
      for (int ks = 0; ks < 2; ++ks) {
        short8v pv;
#pragma unroll
        for (int e = 0; e < 4; ++e) pv[e]     = f2bf(s[2 * ks][e] * inv);
#pragma unroll
        for (int e = 0; e < 4; ++e) pv[4 + e] = f2bf(s[2 * ks + 1][e] * inv);
        pb[ks] = pv;
      }

#pragma unroll
      for (int dt = 0; dt < 2; ++dt) {
        f32x4 o = {0.f, 0.f, 0.f, 0.f};
#pragma unroll
        for (int ks = 0; ks < 2; ++ks) {
          const int va = h * 2176 + (dt * 16 + l15) * 68 + ks * 32 + lhi * 4;
          short8v vfr = cat44(*(const short4v*)&vtm[va], *(const short4v*)&vtm[va + 16]);
          o = mfma16(vfr, pb[ks], o);
        }
        short4v p;
#pragma unroll
        for (int r = 0; r < 4; ++r) p[r] = f2bf(o[r]);
        *(short4v*)&aom[(jt * 16 + l15) * 136 + h * 32 + dt * 16 + lhi * 4] = p;
      }
    }
  }
  __syncthreads();   // B3: aom complete (all heads' columns visible)

  // ---- Phase 3: output projection Y = AO @ proj_w^T + proj_b (ks-outer)
  {
    f32x4 po[2][4];   // [nt][mt] = 32 acc regs
#pragma unroll
    for (int nt = 0; nt < 2; ++nt) {
      const float pbv = proj_b[h * 32 + nt * 16 + l15];
#pragma unroll
      for (int mt = 0; mt < 4; ++mt) po[nt][mt] = f32x4{pbv, pbv, pbv, pbv};
    }
#pragma unroll
    for (int ks = 0; ks < 4; ++ks) {
      short8v p[4];
#pragma unroll
      for (int mt = 0; mt < 4; ++mt)
        p[mt] = *(const short8v*)&aom[(mt * 16 + l15) * 136 + ks * 32 + cb];
#pragma unroll
      for (int nt = 0; nt < 2; ++nt) {
        const short8v wfr =
            *(const short8v*)&wp[(h * 32 + nt * 16 + l15) * 128 + ks * 32 + cb];
#pragma unroll
        for (int mt = 0; mt < 4; ++mt)
          po[nt][mt] = mfma16(p[mt], wfr, po[nt][mt]);
      }
    }
    float* outw = out + (long)b * (49 * 128);
#pragma unroll
    for (int nt = 0; nt < 2; ++nt) {
      const int ncol = h * 32 + nt * 16 + l15;
#pragma unroll
      for (int mt = 0; mt < 4; ++mt)
#pragma unroll
        for (int r = 0; r < 4; ++r) {
          const int m0 = mt * 16 + lhi * 4 + r;
          if (m0 < 49) outw[m0 * 128 + ncol] = po[nt][mt][r];
        }
    }
  }
}

extern "C" void kernel_launch(void* const* d_in, const int* in_sizes, int n_in,
                              void* d_out, int out_size, void* d_ws, size_t ws_size,
                              hipStream_t stream) {
  const float* x          = (const float*)d_in[0];
  const float* mask       = (const float*)d_in[1];
  const float* qkv_w      = (const float*)d_in[2];
  const float* qkv_b      = (const float*)d_in[3];
  const float* proj_w     = (const float*)d_in[4];
  const float* proj_b     = (const float*)d_in[5];
  const float* bias_table = (const float*)d_in[6];

  short* wq  = (short*)d_ws;                         // 384*128 bf16 (98304 B)
  short* wp  = wq + 49152;                           // 128*128 bf16 (32768 B)
  float* cmb = (float*)((char*)d_ws + 131072);       // 4 MB combined bias+mask

  cvt_weights_kernel<<<dim3(192), dim3(256), 0, stream>>>(qkv_w, proj_w, wq, wp);
  build_cmb_kernel<<<dim3(1024), dim3(256), 0, stream>>>(mask, bias_table, cmb);
  win_attn_kernel<<<dim3(4096), dim3(256), 0, stream>>>(
      x, qkv_b, proj_b, wq, wp, cmb, (float*)d_out);
}